// Round 7
// baseline (160.420 us; speedup 1.0000x reference)
//
#include <hip/hip_runtime.h>

#define B_ 8
#define H_ 512
#define W_ 1024
#define NPX (B_*H_*W_)
#define CLEANF 0xAAAAAAAAu

// ---------------- Stage 1 geometry (general path) ----------------
#define TILE 32
#define HD 4
#define RD 40
#define HB 7
#define RB 46
#define HP 8
#define RP 48

__device__ __forceinline__ int clampi(int v, int lo, int hi) {
    return v < lo ? lo : (v > hi ? hi : v);
}
__device__ __forceinline__ int imax(int a, int b) { return a > b ? a : b; }
__device__ __forceinline__ int imin(int a, int b) { return a < b ? a : b; }

// ---------------- Gaussian weights ----------------
#define GW0 0.39905027965f
#define GW1 0.24203622800f
#define GW2 0.05400558260f
#define GW3 0.00443304810f

// cross-max (includes center; duplicates harmless) and 3x3 min; viol = NOT boundary
#define VIOL9(L,C,R, UL,UC,UR, DL,DC,DR, OUT)                                   \
    {                                                                           \
        int mx = imax(imax(UC, DC), imax(L, R));                                \
        int mn = imin(imin(imin(L, C), imin(R, UL)),                            \
                      imin(imin(UC, UR), imin(DL, imin(DC, DR))));              \
        OUT = !((mx > (C)) || (mn < (C)));                                      \
    }

// ---- K1: per-row boundary check (atomic tile marking) + H-pass of x -> midH ----
__global__ __launch_bounds__(256)
void k_checkH(const float* __restrict__ xg, const int* __restrict__ predg,
              float* __restrict__ midH, unsigned int* __restrict__ flags)
{
    const int tid = threadIdx.x;
    const int grow = blockIdx.x;                 // img*H + y
    const int img = grow >> 9, y = grow & (H_ - 1);
    const int gx0 = tid * 4;

    const int* prow  = predg + (size_t)grow * W_;
    const int* purow = predg + (size_t)((y == 0)      ? grow : grow - 1) * W_;
    const int* pdrow = predg + (size_t)((y == H_ - 1) ? grow : grow + 1) * W_;

    const int4 c4 = *(const int4*)(prow  + gx0);
    const int4 u4 = *(const int4*)(purow + gx0);
    const int4 d4 = *(const int4*)(pdrow + gx0);
    const int xl = (gx0 == 0) ? 0 : gx0 - 1;
    const int xr = (gx0 + 4 > W_ - 1) ? W_ - 1 : gx0 + 4;
    const int cc0 = prow[xl],  uu0 = purow[xl], dd0 = pdrow[xl];
    const int cc5 = prow[xr],  uu5 = purow[xr], dd5 = pdrow[xr];
    const int cc1 = c4.x, cc2 = c4.y, cc3 = c4.z, cc4 = c4.w;
    const int uu1 = u4.x, uu2 = u4.y, uu3 = u4.z, uu4 = u4.w;
    const int dd1 = d4.x, dd2 = d4.y, dd3 = d4.z, dd4 = d4.w;

    bool v0, v1, v2, v3;
    VIOL9(cc0, cc1, cc2, uu0, uu1, uu2, dd0, dd1, dd2, v0);
    VIOL9(cc1, cc2, cc3, uu1, uu2, uu3, dd1, dd2, dd3, v1);
    VIOL9(cc2, cc3, cc4, uu2, uu3, uu4, dd2, dd3, dd4, v2);
    VIOL9(cc3, cc4, cc5, uu3, uu4, uu5, dd3, dd4, dd5, v3);

    if (v0 | v1 | v2 | v3) {       // ~never taken (P ~ 1.5e-6 per px)
        const int ty0 = ((y == 0) ? y : y - 1) >> 5;
        const int ty1 = ((y == H_ - 1) ? y : y + 1) >> 5;
        const bool vj[4] = {v0, v1, v2, v3};
        #pragma unroll
        for (int j = 0; j < 4; ++j) {
            if (vj[j]) {
                int gx = gx0 + j;
                int tx0 = ((gx == 0) ? gx : gx - 1) >> 5;
                int tx1 = ((gx == W_ - 1) ? gx : gx + 1) >> 5;
                for (int ty = ty0; ty <= ty1; ++ty)
                    for (int tx = tx0; tx <= tx1; ++tx)
                        atomicExch(&flags[(((img << 4) + ty) << 5) + tx], 1u);
            }
        }
    }

    // ---- H pass of x (validated r5) ----
    const float* rp = xg   + (size_t)grow * W_;
    float*       wp = midH + (size_t)grow * W_;
    float4 o;
    if (tid >= 5 && tid <= 250) {
        const float4* vp = (const float4*)(rp + gx0 - 20);
        float4 fm5 = vp[0], fm4 = vp[1], fm3 = vp[2], fm2 = vp[3], fm1 = vp[4];
        float4 f0 = vp[5], f1 = vp[6], f2 = vp[7], f3 = vp[8], f4 = vp[9], f5 = vp[10];
        o.x = GW0 * f0.x + GW1 * (fm2.z + f1.z) + GW2 * (fm3.x + f3.x) + GW3 * (fm5.z + f4.z);
        o.y = GW0 * f0.y + GW1 * (fm2.w + f1.w) + GW2 * (fm3.y + f3.y) + GW3 * (fm5.w + f4.w);
        o.z = GW0 * f0.z + GW1 * (fm1.x + f2.x) + GW2 * (fm3.z + f3.z) + GW3 * (fm4.x + f5.x);
        o.w = GW0 * f0.w + GW1 * (fm1.y + f2.y) + GW2 * (fm3.w + f3.w) + GW3 * (fm4.y + f5.y);
    } else {
        float r[4];
        #pragma unroll
        for (int j = 0; j < 4; ++j) {
            int gx = gx0 + j;
            r[j] = GW3 * (rp[clampi(gx - 18, 0, W_ - 1)] + rp[clampi(gx + 18, 0, W_ - 1)])
                 + GW2 * (rp[clampi(gx - 12, 0, W_ - 1)] + rp[clampi(gx + 12, 0, W_ - 1)])
                 + GW1 * (rp[clampi(gx - 6,  0, W_ - 1)] + rp[clampi(gx + 6,  0, W_ - 1)])
                 + GW0 *  rp[gx];
        }
        o.x = r[0]; o.y = r[1]; o.z = r[2]; o.w = r[3];
    }
    *(float4*)(wp + gx0) = o;
}

// ---- K2: V pass (validated r5) ----
__global__ __launch_bounds__(256)
void gaussV(const float* __restrict__ in, float* __restrict__ out)
{
    const int tid = threadIdx.x;
    const int y   = blockIdx.x & (H_ - 1);
    const int img = blockIdx.x >> 9;
    const float* pl = in  + (size_t)img * H_ * W_;
    float*       wp = out + (size_t)blockIdx.x * W_;
    const int gx0 = tid * 4;

    const float* r0 = pl + (size_t)clampi(y - 18, 0, H_ - 1) * W_ + gx0;
    const float* r1 = pl + (size_t)clampi(y - 12, 0, H_ - 1) * W_ + gx0;
    const float* r2 = pl + (size_t)clampi(y - 6,  0, H_ - 1) * W_ + gx0;
    const float* r3 = pl + (size_t)y * W_ + gx0;
    const float* r4 = pl + (size_t)clampi(y + 6,  0, H_ - 1) * W_ + gx0;
    const float* r5 = pl + (size_t)clampi(y + 12, 0, H_ - 1) * W_ + gx0;
    const float* r6 = pl + (size_t)clampi(y + 18, 0, H_ - 1) * W_ + gx0;

    float4 a0 = *(const float4*)r0, a1 = *(const float4*)r1, a2 = *(const float4*)r2;
    float4 a3 = *(const float4*)r3, a4 = *(const float4*)r4, a5 = *(const float4*)r5;
    float4 a6 = *(const float4*)r6;

    float4 o;
    o.x = GW3 * (a0.x + a6.x) + GW2 * (a1.x + a5.x) + GW1 * (a2.x + a4.x) + GW0 * a3.x;
    o.y = GW3 * (a0.y + a6.y) + GW2 * (a1.y + a5.y) + GW1 * (a2.y + a4.y) + GW0 * a3.y;
    o.z = GW3 * (a0.z + a6.z) + GW2 * (a1.z + a5.z) + GW1 * (a2.z + a4.z) + GW0 * a3.z;
    o.w = GW3 * (a0.w + a6.w) + GW2 * (a1.w + a5.w) + GW1 * (a2.w + a4.w) + GW0 * a3.w;
    *(float4*)(wp + gx0) = o;
}

// ---- K3a: stage1 general path for dirty tiles only (early exit) ----
__global__ __launch_bounds__(256)
void k_mid(const float* __restrict__ xg, const int* __restrict__ predg,
           const unsigned int* __restrict__ flags, float* __restrict__ midg)
{
    const int tileId = (((blockIdx.z << 4) + blockIdx.y) << 5) + blockIdx.x;
    if (flags[tileId] == CLEANF) return;

    __shared__ int sScratch[3200];              // union: pred 48x48 / sHX+sHM
    __shared__ unsigned long long sB[4][RB];

    __shared__ float sA[RD * RD];
    __shared__ float sC[RD * RD];
    int*   sPred = sScratch;
    float* sHX = (float*)sScratch;
    float* sHM = (float*)sScratch + RD * RD;

    const int tid = threadIdx.x;
    const int x0 = blockIdx.x * TILE;
    const int y0 = blockIdx.y * TILE;
    const size_t plane = (size_t)H_ * W_;
    const int*   pp = predg + blockIdx.z * plane;
    const float* xp = xg    + blockIdx.z * plane;
    float*       op = midg  + blockIdx.z * plane;

    const bool leftB  = (x0 == 0), rightB = (x0 + TILE == W_);
    const bool topB   = (y0 == 0), botB   = (y0 + TILE == H_);
    const bool borderB = leftB || rightB || topB || botB;

    for (int i = tid; i < RP * RP; i += 256) {
        int ry = i / RP, rx = i - ry * RP;
        int gy = y0 - HP + ry, gx = x0 - HP + rx;
        sPred[i] = (gy >= 0 && gy < H_ && gx >= 0 && gx < W_) ? pp[(size_t)gy * W_ + gx] : -1;
    }
    for (int i = tid; i < RD * RD; i += 256) {
        int ry = i / RD, rx = i - ry * RD;
        int gy = clampi(y0 - HD + ry, 0, H_ - 1);
        int gx = clampi(x0 - HD + rx, 0, W_ - 1);
        sA[i] = xp[(size_t)gy * W_ + gx];
    }
    __syncthreads();

    const int lane = tid & 63, wv = tid >> 6;
    {   // b0 via ballot
        for (int row = wv; row < RB; row += 4) {
            bool bp = false;
            if (lane < RB) {
                const int py = row + 1, px = lane + 1;
                int c = sPred[py * RP + px];
                if (c >= 0) {
                    int up = sPred[(py - 1) * RP + px];
                    int dn = sPred[(py + 1) * RP + px];
                    int lf = sPred[py * RP + px - 1];
                    int rt = sPred[py * RP + px + 1];
                    int ul = sPred[(py - 1) * RP + px - 1];
                    int ur = sPred[(py - 1) * RP + px + 1];
                    int dl = sPred[(py + 1) * RP + px - 1];
                    int dr = sPred[(py + 1) * RP + px + 1];
                    int mx = imax(imax(up, dn), imax(lf, rt));
                    int Bv = 0x7fffffff;
                    int mn = imin(imin(imin(up < 0 ? Bv : up, dn < 0 ? Bv : dn),
                                       imin(lf < 0 ? Bv : lf, rt < 0 ? Bv : rt)),
                                  imin(imin(ul < 0 ? Bv : ul, ur < 0 ? Bv : ur),
                                       imin(dl < 0 ? Bv : dl, dr < 0 ? Bv : dr)));
                    bp = (mx > c) || (mn < c);
                }
            }
            unsigned long long bal = __ballot(bp);
            if (lane == 0) sB[0][row] = bal;
        }
    }

    #pragma unroll
    for (int lvl = 1; lvl < 4; ++lvl) {
        __syncthreads();
        if (tid < RB) {
            unsigned long long c = sB[lvl - 1][tid];
            unsigned long long u = (tid > 0)      ? sB[lvl - 1][tid - 1] : 0ULL;
            unsigned long long d = (tid < RB - 1) ? sB[lvl - 1][tid + 1] : 0ULL;
            sB[lvl][tid] = c | (c << 1) | (c >> 1) | u | d;
        }
    }
    __syncthreads();

    if (borderB) {
        const bool act = tid < 4 * RB;
        unsigned long long val = 0; int lvl = 0, row = 0;
        if (act) {
            lvl = tid / RB; row = tid - lvl * RB;
            int srcRow = clampi(row, topB ? HB : 0, botB ? (RB - 1 - HB) : RB - 1);
            val = sB[lvl][srcRow];
            if (leftB) {
                unsigned long long b = (val >> HB) & 1ULL;
                unsigned long long lo = (1ULL << HB) - 1;
                val = (val & ~lo) | (b ? lo : 0ULL);
            }
            if (rightB) {
                const int jb = RB - 1 - HB;
                unsigned long long b = (val >> jb) & 1ULL;
                unsigned long long keep = (1ULL << (jb + 1)) - 1;
                unsigned long long hi = (((1ULL << RB) - 1) & ~keep);
                val = (val & keep) | (b ? hi : 0ULL);
            }
        }
        __syncthreads();
        if (act) sB[lvl][row] = val;
    }
    __syncthreads();

    float* cur = sA;
    float* nxt = sC;
    #pragma unroll
    for (int it = 0; it < 4; ++it) {
        const int r = 3 - it;
        const unsigned long long* br = sB[r];

        for (int i = tid; i < RD * RD; i += 256) {
            int ry = i / RD, rx = i - ry * RD;
            unsigned long long row = br[ry + (HB - HD)];
            int rxm = rx > 0 ? rx - 1 : 0;
            int rxp = rx < RD - 1 ? rx + 1 : RD - 1;
            float m0 = ((row >> (rx + 2)) & 1ULL) ? 0.f : 1.f;
            float m1 = ((row >> (rx + 3)) & 1ULL) ? 0.f : 1.f;
            float m2 = ((row >> (rx + 4)) & 1ULL) ? 0.f : 1.f;
            float a0 = cur[ry * RD + rxm];
            float a1 = cur[ry * RD + rx];
            float a2 = cur[ry * RD + rxp];
            sHX[i] = m0 * a0 + m1 * a1 + m2 * a2;
            sHM[i] = m0 + m1 + m2;
        }
        __syncthreads();

        for (int i = tid; i < 38 * 38; i += 256) {
            int q = i / 38;
            int ry = 1 + q, rx = 1 + (i - q * 38);
            int idx = ry * RD + rx;
            float n = sHM[idx - RD] + sHM[idx] + sHM[idx + RD];
            float y = sHX[idx - RD] + sHX[idx] + sHX[idx + RD];
            float c = cur[idx];
            unsigned long long row = br[ry + (HB - HD)];
            bool masked = ((row >> (rx + 3)) & 1ULL) != 0ULL;
            float avg = y * __builtin_amdgcn_rcpf(n);
            nxt[idx] = (masked && n > 0.5f) ? avg : c;
        }
        __syncthreads();

        if (borderB) {
            for (int i = tid; i < RD * RD; i += 256) {
                int ry = i / RD, rx = i - ry * RD;
                int ryc = clampi(ry, topB ? HD : 0, botB ? (RD - 1 - HD) : RD - 1);
                int rxc = clampi(rx, leftB ? HD : 0, rightB ? (RD - 1 - HD) : RD - 1);
                if (ryc != ry || rxc != rx) nxt[i] = nxt[ryc * RD + rxc];
            }
        }
        __syncthreads();
        float* t = cur; cur = nxt; nxt = t;
    }

    for (int i = tid; i < TILE * TILE; i += 256) {
        int ty = i >> 5, tx = i & 31;
        op[(size_t)(y0 + ty) * W_ + (x0 + tx)] = cur[(ty + HD) * RD + (tx + HD)];
    }
}

// ---- K3b: patch output tiles within reach of a dirty tile (early exit) ----
__global__ __launch_bounds__(256)
void k_patch(const float* __restrict__ xg, const float* __restrict__ midg,
             const unsigned int* __restrict__ flags, float* __restrict__ outg)
{
    const int tx = blockIdx.x, ty = blockIdx.y, img = blockIdx.z;

    bool dirty = false;
    #pragma unroll
    for (int dy = -1; dy <= 1; ++dy)
        #pragma unroll
        for (int dx = -1; dx <= 1; ++dx) {
            int tyy = ty + dy, txx = tx + dx;
            if (tyy >= 0 && tyy < 16 && txx >= 0 && txx < 32)
                dirty |= (flags[(((img << 4) + tyy) << 5) + txx] != CLEANF);
        }
    if (!dirty) return;

    const size_t plane = (size_t)H_ * W_;
    const float* xp = xg   + (size_t)img * plane;
    const float* mp = midg + (size_t)img * plane;
    float*       op = outg + (size_t)img * plane;
    const int x0 = tx * TILE, y0 = ty * TILE;
    const float w[7] = {GW3, GW2, GW1, GW0, GW1, GW2, GW3};

    for (int i = threadIdx.x; i < TILE * TILE; i += 256) {
        const int py = y0 + (i >> 5);
        const int px = x0 + (i & 31);
        float acc = 0.f;
        #pragma unroll
        for (int j = 0; j < 7; ++j) {
            const int qy = clampi(py + 6 * (j - 3), 0, H_ - 1);
            const float* xr = xp + (size_t)qy * W_;
            const float* mr = mp + (size_t)qy * W_;
            const int frow = ((img << 4) + (qy >> 5)) << 5;
            float rowacc = 0.f;
            #pragma unroll
            for (int k = 0; k < 7; ++k) {
                const int qx = clampi(px + 6 * (k - 3), 0, W_ - 1);
                const float v = (flags[frow + (qx >> 5)] != CLEANF) ? mr[qx] : xr[qx];
                rowacc += w[k] * v;
            }
            acc += w[j] * rowacc;
        }
        op[(size_t)py * W_ + px] = acc;
    }
}

extern "C" void kernel_launch(void* const* d_in, const int* in_sizes, int n_in,
                              void* d_out, int out_size, void* d_ws, size_t ws_size,
                              hipStream_t stream) {
    const float* x    = (const float*)d_in[0];
    const int*   pred = (const int*)d_in[1];
    float*       out  = (float*)d_out;

    float* midH = (float*)d_ws;                              // plane 0
    float* mid  = (float*)d_ws + NPX;                        // plane 1
    unsigned int* flags = (unsigned int*)((char*)d_ws + 2 * (size_t)NPX * 4); // 16 KB
    // ws poison 0xAA == CLEANF sentinel; any other value => tile treated dirty
    // (degrades to slow-but-correct if poison semantics ever change)

    k_checkH<<<B_ * H_, 256, 0, stream>>>(x, pred, midH, flags);
    gaussV  <<<B_ * H_, 256, 0, stream>>>(midH, out);
    k_mid   <<<dim3(32, 16, B_), 256, 0, stream>>>(x, pred, flags, mid);
    k_patch <<<dim3(32, 16, B_), 256, 0, stream>>>(x, mid, flags, out);
}

// Round 8
// 128.027 us; speedup vs baseline: 1.2530x; 1.2530x over previous
//
#include <hip/hip_runtime.h>

#define B_ 8
#define H_ 512
#define W_ 1024
#define NPX (B_*H_*W_)

// ---------------- Stage 1 geometry (general path) ----------------
#define TILE 32
#define HD 4
#define RD 40
#define HB 7
#define RB 46
#define HP 8
#define RP 48

__device__ __forceinline__ int clampi(int v, int lo, int hi) {
    return v < lo ? lo : (v > hi ? hi : v);
}
__device__ __forceinline__ int imax(int a, int b) { return a > b ? a : b; }
__device__ __forceinline__ int imin(int a, int b) { return a < b ? a : b; }

// ---------------- Gaussian weights ----------------
#define GW0 0.39905027965f
#define GW1 0.24203622800f
#define GW2 0.05400558260f
#define GW3 0.00443304810f

// cross-max (includes center; duplicates harmless) and 3x3 min; viol = NOT boundary
#define VIOL9(L,C,R, UL,UC,UR, DL,DC,DR, OUT)                                   \
    {                                                                           \
        int mx = imax(imax(UC, DC), imax(L, R));                                \
        int mn = imin(imin(imin(L, C), imin(R, UL)),                            \
                      imin(imin(UC, UR), imin(DL, imin(DC, DR))));              \
        OUT = !((mx > (C)) || (mn < (C)));                                      \
    }

// ---- K1: per-row boundary check (tile marking) + H-pass of x -> midH ----
__global__ __launch_bounds__(256)
void k_checkH(const float* __restrict__ xg, const int* __restrict__ predg,
              float* __restrict__ midH, unsigned int* __restrict__ flags)
{
    const int tid = threadIdx.x;
    const int grow = blockIdx.x;                 // img*H + y
    const int img = grow >> 9, y = grow & (H_ - 1);
    const int gx0 = tid * 4;

    const int* prow  = predg + (size_t)grow * W_;
    const int* purow = predg + (size_t)((y == 0)      ? grow : grow - 1) * W_;
    const int* pdrow = predg + (size_t)((y == H_ - 1) ? grow : grow + 1) * W_;

    const int4 c4 = *(const int4*)(prow  + gx0);
    const int4 u4 = *(const int4*)(purow + gx0);
    const int4 d4 = *(const int4*)(pdrow + gx0);
    const int xl = (gx0 == 0) ? 0 : gx0 - 1;
    const int xr = (gx0 + 4 > W_ - 1) ? W_ - 1 : gx0 + 4;
    const int cc0 = prow[xl],  uu0 = purow[xl], dd0 = pdrow[xl];
    const int cc5 = prow[xr],  uu5 = purow[xr], dd5 = pdrow[xr];
    const int cc1 = c4.x, cc2 = c4.y, cc3 = c4.z, cc4 = c4.w;
    const int uu1 = u4.x, uu2 = u4.y, uu3 = u4.z, uu4 = u4.w;
    const int dd1 = d4.x, dd2 = d4.y, dd3 = d4.z, dd4 = d4.w;

    bool v0, v1, v2, v3;
    VIOL9(cc0, cc1, cc2, uu0, uu1, uu2, dd0, dd1, dd2, v0);
    VIOL9(cc1, cc2, cc3, uu1, uu2, uu3, dd1, dd2, dd3, v1);
    VIOL9(cc2, cc3, cc4, uu2, uu3, uu4, dd2, dd3, dd4, v2);
    VIOL9(cc3, cc4, cc5, uu3, uu4, uu5, dd3, dd4, dd5, v3);

    if (v0 | v1 | v2 | v3) {       // ~never taken (P ~ 1.5e-6 per px)
        const int ty0 = ((y == 0) ? y : y - 1) >> 5;
        const int ty1 = ((y == H_ - 1) ? y : y + 1) >> 5;
        const bool vj[4] = {v0, v1, v2, v3};
        #pragma unroll
        for (int j = 0; j < 4; ++j) {
            if (vj[j]) {
                int gx = gx0 + j;
                int tx0 = ((gx == 0) ? gx : gx - 1) >> 5;
                int tx1 = ((gx == W_ - 1) ? gx : gx + 1) >> 5;
                for (int ty = ty0; ty <= ty1; ++ty)
                    for (int tx = tx0; tx <= tx1; ++tx)
                        atomicExch(&flags[(((img << 4) + ty) << 5) + tx], 1u);
            }
        }
    }

    // ---- H pass of x (validated r5) ----
    const float* rp = xg   + (size_t)grow * W_;
    float*       wp = midH + (size_t)grow * W_;
    float4 o;
    if (tid >= 5 && tid <= 250) {
        const float4* vp = (const float4*)(rp + gx0 - 20);
        float4 fm5 = vp[0], fm4 = vp[1], fm3 = vp[2], fm2 = vp[3], fm1 = vp[4];
        float4 f0 = vp[5], f1 = vp[6], f2 = vp[7], f3 = vp[8], f4 = vp[9], f5 = vp[10];
        o.x = GW0 * f0.x + GW1 * (fm2.z + f1.z) + GW2 * (fm3.x + f3.x) + GW3 * (fm5.z + f4.z);
        o.y = GW0 * f0.y + GW1 * (fm2.w + f1.w) + GW2 * (fm3.y + f3.y) + GW3 * (fm5.w + f4.w);
        o.z = GW0 * f0.z + GW1 * (fm1.x + f2.x) + GW2 * (fm3.z + f3.z) + GW3 * (fm4.x + f5.x);
        o.w = GW0 * f0.w + GW1 * (fm1.y + f2.y) + GW2 * (fm3.w + f3.w) + GW3 * (fm4.y + f5.y);
    } else {
        float r[4];
        #pragma unroll
        for (int j = 0; j < 4; ++j) {
            int gx = gx0 + j;
            r[j] = GW3 * (rp[clampi(gx - 18, 0, W_ - 1)] + rp[clampi(gx + 18, 0, W_ - 1)])
                 + GW2 * (rp[clampi(gx - 12, 0, W_ - 1)] + rp[clampi(gx + 12, 0, W_ - 1)])
                 + GW1 * (rp[clampi(gx - 6,  0, W_ - 1)] + rp[clampi(gx + 6,  0, W_ - 1)])
                 + GW0 *  rp[gx];
        }
        o.x = r[0]; o.y = r[1]; o.z = r[2]; o.w = r[3];
    }
    *(float4*)(wp + gx0) = o;
}

// ---- K2: stage1 general path for dirty tiles only (early exit) ----
__global__ __launch_bounds__(256)
void k_mid(const float* __restrict__ xg, const int* __restrict__ predg,
           const unsigned int* __restrict__ flags, float* __restrict__ midg)
{
    const int tileId = (((blockIdx.z << 4) + blockIdx.y) << 5) + blockIdx.x;
    if (flags[tileId] != 1u) return;

    __shared__ int sScratch[3200];              // union: pred 48x48 / sHX+sHM
    __shared__ unsigned long long sB[4][RB];
    __shared__ float sA[RD * RD];
    __shared__ float sC[RD * RD];
    int*   sPred = sScratch;
    float* sHX = (float*)sScratch;
    float* sHM = (float*)sScratch + RD * RD;

    const int tid = threadIdx.x;
    const int x0 = blockIdx.x * TILE;
    const int y0 = blockIdx.y * TILE;
    const size_t plane = (size_t)H_ * W_;
    const int*   pp = predg + blockIdx.z * plane;
    const float* xp = xg    + blockIdx.z * plane;
    float*       op = midg  + blockIdx.z * plane;

    const bool leftB  = (x0 == 0), rightB = (x0 + TILE == W_);
    const bool topB   = (y0 == 0), botB   = (y0 + TILE == H_);
    const bool borderB = leftB || rightB || topB || botB;

    for (int i = tid; i < RP * RP; i += 256) {
        int ry = i / RP, rx = i - ry * RP;
        int gy = y0 - HP + ry, gx = x0 - HP + rx;
        sPred[i] = (gy >= 0 && gy < H_ && gx >= 0 && gx < W_) ? pp[(size_t)gy * W_ + gx] : -1;
    }
    for (int i = tid; i < RD * RD; i += 256) {
        int ry = i / RD, rx = i - ry * RD;
        int gy = clampi(y0 - HD + ry, 0, H_ - 1);
        int gx = clampi(x0 - HD + rx, 0, W_ - 1);
        sA[i] = xp[(size_t)gy * W_ + gx];
    }
    __syncthreads();

    const int lane = tid & 63, wv = tid >> 6;
    {   // b0 via ballot
        for (int row = wv; row < RB; row += 4) {
            bool bp = false;
            if (lane < RB) {
                const int py = row + 1, px = lane + 1;
                int c = sPred[py * RP + px];
                if (c >= 0) {
                    int up = sPred[(py - 1) * RP + px];
                    int dn = sPred[(py + 1) * RP + px];
                    int lf = sPred[py * RP + px - 1];
                    int rt = sPred[py * RP + px + 1];
                    int ul = sPred[(py - 1) * RP + px - 1];
                    int ur = sPred[(py - 1) * RP + px + 1];
                    int dl = sPred[(py + 1) * RP + px - 1];
                    int dr = sPred[(py + 1) * RP + px + 1];
                    int mx = imax(imax(up, dn), imax(lf, rt));
                    int Bv = 0x7fffffff;
                    int mn = imin(imin(imin(up < 0 ? Bv : up, dn < 0 ? Bv : dn),
                                       imin(lf < 0 ? Bv : lf, rt < 0 ? Bv : rt)),
                                  imin(imin(ul < 0 ? Bv : ul, ur < 0 ? Bv : ur),
                                       imin(dl < 0 ? Bv : dl, dr < 0 ? Bv : dr)));
                    bp = (mx > c) || (mn < c);
                }
            }
            unsigned long long bal = __ballot(bp);
            if (lane == 0) sB[0][row] = bal;
        }
    }

    #pragma unroll
    for (int lvl = 1; lvl < 4; ++lvl) {
        __syncthreads();
        if (tid < RB) {
            unsigned long long c = sB[lvl - 1][tid];
            unsigned long long u = (tid > 0)      ? sB[lvl - 1][tid - 1] : 0ULL;
            unsigned long long d = (tid < RB - 1) ? sB[lvl - 1][tid + 1] : 0ULL;
            sB[lvl][tid] = c | (c << 1) | (c >> 1) | u | d;
        }
    }
    __syncthreads();

    if (borderB) {
        const bool act = tid < 4 * RB;
        unsigned long long val = 0; int lvl = 0, row = 0;
        if (act) {
            lvl = tid / RB; row = tid - lvl * RB;
            int srcRow = clampi(row, topB ? HB : 0, botB ? (RB - 1 - HB) : RB - 1);
            val = sB[lvl][srcRow];
            if (leftB) {
                unsigned long long b = (val >> HB) & 1ULL;
                unsigned long long lo = (1ULL << HB) - 1;
                val = (val & ~lo) | (b ? lo : 0ULL);
            }
            if (rightB) {
                const int jb = RB - 1 - HB;
                unsigned long long b = (val >> jb) & 1ULL;
                unsigned long long keep = (1ULL << (jb + 1)) - 1;
                unsigned long long hi = (((1ULL << RB) - 1) & ~keep);
                val = (val & keep) | (b ? hi : 0ULL);
            }
        }
        __syncthreads();
        if (act) sB[lvl][row] = val;
    }
    __syncthreads();

    float* cur = sA;
    float* nxt = sC;
    #pragma unroll
    for (int it = 0; it < 4; ++it) {
        const int r = 3 - it;
        const unsigned long long* br = sB[r];

        for (int i = tid; i < RD * RD; i += 256) {
            int ry = i / RD, rx = i - ry * RD;
            unsigned long long row = br[ry + (HB - HD)];
            int rxm = rx > 0 ? rx - 1 : 0;
            int rxp = rx < RD - 1 ? rx + 1 : RD - 1;
            float m0 = ((row >> (rx + 2)) & 1ULL) ? 0.f : 1.f;
            float m1 = ((row >> (rx + 3)) & 1ULL) ? 0.f : 1.f;
            float m2 = ((row >> (rx + 4)) & 1ULL) ? 0.f : 1.f;
            float a0 = cur[ry * RD + rxm];
            float a1 = cur[ry * RD + rx];
            float a2 = cur[ry * RD + rxp];
            sHX[i] = m0 * a0 + m1 * a1 + m2 * a2;
            sHM[i] = m0 + m1 + m2;
        }
        __syncthreads();

        for (int i = tid; i < 38 * 38; i += 256) {
            int q = i / 38;
            int ry = 1 + q, rx = 1 + (i - q * 38);
            int idx = ry * RD + rx;
            float n = sHM[idx - RD] + sHM[idx] + sHM[idx + RD];
            float y = sHX[idx - RD] + sHX[idx] + sHX[idx + RD];
            float c = cur[idx];
            unsigned long long row = br[ry + (HB - HD)];
            bool masked = ((row >> (rx + 3)) & 1ULL) != 0ULL;
            float avg = y * __builtin_amdgcn_rcpf(n);
            nxt[idx] = (masked && n > 0.5f) ? avg : c;
        }
        __syncthreads();

        if (borderB) {
            for (int i = tid; i < RD * RD; i += 256) {
                int ry = i / RD, rx = i - ry * RD;
                int ryc = clampi(ry, topB ? HD : 0, botB ? (RD - 1 - HD) : RD - 1);
                int rxc = clampi(rx, leftB ? HD : 0, rightB ? (RD - 1 - HD) : RD - 1);
                if (ryc != ry || rxc != rx) nxt[i] = nxt[ryc * RD + rxc];
            }
        }
        __syncthreads();
        float* t = cur; cur = nxt; nxt = t;
    }

    for (int i = tid; i < TILE * TILE; i += 256) {
        int ty = i >> 5, tx = i & 31;
        op[(size_t)(y0 + ty) * W_ + (x0 + tx)] = cur[(ty + HD) * RD + (tx + HD)];
    }
}

// ---- K3: fix midH rows overlapping a dirty tile (H-side correction, 7 taps) ----
// midH[y][c] is wrong iff some tap (y, clamp(c+6k)) lies in a flagged tile.
// For dirty tile (tr,tc): rows y0..y0+31, cols x0-18..x0+49. Overlapping bands
// from adjacent dirty tiles write identical values (benign).
__global__ __launch_bounds__(256)
void k_fixH(const float* __restrict__ xg, const float* __restrict__ midg,
            const unsigned int* __restrict__ flags, float* __restrict__ midH)
{
    const int img = blockIdx.z;
    const int tileId = (((img << 4) + blockIdx.y) << 5) + blockIdx.x;
    if (flags[tileId] != 1u) return;

    const size_t plane = (size_t)H_ * W_;
    const float* xp = xg   + (size_t)img * plane;
    const float* mp = midg + (size_t)img * plane;
    const int x0 = blockIdx.x * TILE, y0 = blockIdx.y * TILE;
    const float w[7] = {GW3, GW2, GW1, GW0, GW1, GW2, GW3};

    for (int i = threadIdx.x; i < 32 * 68; i += 256) {
        const int r  = i / 68;
        const int gy = y0 + r;
        const int gx = x0 - 18 + (i - r * 68);
        if (gx < 0 || gx >= W_) continue;
        const float* xr = xp + (size_t)gy * W_;
        const float* mr = mp + (size_t)gy * W_;
        const int frow = ((img << 4) + (gy >> 5)) << 5;
        float acc = 0.f;
        #pragma unroll
        for (int k = 0; k < 7; ++k) {
            const int q = clampi(gx + 6 * (k - 3), 0, W_ - 1);
            const float v = (flags[frow + (q >> 5)] == 1u) ? mr[q] : xr[q];
            acc += w[k] * v;
        }
        midH[(size_t)(img * H_ + gy) * W_ + gx] = acc;
    }
}

// ---- K4: V pass (validated r5) -- exact, since midH is fully corrected ----
__global__ __launch_bounds__(256)
void gaussV(const float* __restrict__ in, float* __restrict__ out)
{
    const int tid = threadIdx.x;
    const int y   = blockIdx.x & (H_ - 1);
    const int img = blockIdx.x >> 9;
    const float* pl = in  + (size_t)img * H_ * W_;
    float*       wp = out + (size_t)blockIdx.x * W_;
    const int gx0 = tid * 4;

    const float* r0 = pl + (size_t)clampi(y - 18, 0, H_ - 1) * W_ + gx0;
    const float* r1 = pl + (size_t)clampi(y - 12, 0, H_ - 1) * W_ + gx0;
    const float* r2 = pl + (size_t)clampi(y - 6,  0, H_ - 1) * W_ + gx0;
    const float* r3 = pl + (size_t)y * W_ + gx0;
    const float* r4 = pl + (size_t)clampi(y + 6,  0, H_ - 1) * W_ + gx0;
    const float* r5 = pl + (size_t)clampi(y + 12, 0, H_ - 1) * W_ + gx0;
    const float* r6 = pl + (size_t)clampi(y + 18, 0, H_ - 1) * W_ + gx0;

    float4 a0 = *(const float4*)r0, a1 = *(const float4*)r1, a2 = *(const float4*)r2;
    float4 a3 = *(const float4*)r3, a4 = *(const float4*)r4, a5 = *(const float4*)r5;
    float4 a6 = *(const float4*)r6;

    float4 o;
    o.x = GW3 * (a0.x + a6.x) + GW2 * (a1.x + a5.x) + GW1 * (a2.x + a4.x) + GW0 * a3.x;
    o.y = GW3 * (a0.y + a6.y) + GW2 * (a1.y + a5.y) + GW1 * (a2.y + a4.y) + GW0 * a3.y;
    o.z = GW3 * (a0.z + a6.z) + GW2 * (a1.z + a5.z) + GW1 * (a2.z + a4.z) + GW0 * a3.z;
    o.w = GW3 * (a0.w + a6.w) + GW2 * (a1.w + a5.w) + GW1 * (a2.w + a4.w) + GW0 * a3.w;
    *(float4*)(wp + gx0) = o;
}

extern "C" void kernel_launch(void* const* d_in, const int* in_sizes, int n_in,
                              void* d_out, int out_size, void* d_ws, size_t ws_size,
                              hipStream_t stream) {
    const float* x    = (const float*)d_in[0];
    const int*   pred = (const int*)d_in[1];
    float*       out  = (float*)d_out;

    float* midH = (float*)d_ws;                              // plane 0
    float* mid  = (float*)d_ws + NPX;                        // plane 1
    unsigned int* flags = (unsigned int*)((char*)d_ws + 2 * (size_t)NPX * 4); // 16 KB
    // dirty <=> flags == 1u (written by k_checkH); any other value (incl. 0xAA
    // poison) means clean. k_checkH deterministically re-marks every call.

    k_checkH<<<B_ * H_, 256, 0, stream>>>(x, pred, midH, flags);
    k_mid   <<<dim3(32, 16, B_), 256, 0, stream>>>(x, pred, flags, mid);
    k_fixH  <<<dim3(32, 16, B_), 256, 0, stream>>>(x, mid, flags, midH);
    gaussV  <<<B_ * H_, 256, 0, stream>>>(midH, out);
}